// Round 6
// baseline (98.673 us; speedup 1.0000x reference)
//
#include <hip/hip_runtime.h>
#include <math.h>

#define BB   64
#define CC   64
#define HH   112
#define WW   112
#define HIDN 256
#define PLANE   (HH * WW)      // 12544
#define PLANE4  (PLANE / 4)    // 3136 float4 per plane
#define BODY4   3072           // 12 * 256
#define ROW4    (WW / 4)       // 28

typedef float fvec4 __attribute__((ext_vector_type(4)));

// ---------------- Kernel 1: global average pool per (b,c) plane ----------------
// Cached loads on purpose: x (205 MB) fits in the 256 MB L3 and is re-read
// every replay -> keep it resident.
__global__ __launch_bounds__(256) void pool_kernel(const float* __restrict__ x,
                                                   float* __restrict__ xfeat) {
    int plane = blockIdx.x;  // b*CC + c
    const fvec4* p = (const fvec4*)(x + (size_t)plane * PLANE);
    int t = threadIdx.x;
    float s0 = 0.f, s1 = 0.f, s2 = 0.f, s3 = 0.f;
    #pragma unroll
    for (int i = t; i < BODY4; i += 256) {
        fvec4 v = p[i];
        s0 += v.x; s1 += v.y; s2 += v.z; s3 += v.w;
    }
    if (t < PLANE4 - BODY4) {
        fvec4 v = p[BODY4 + t];
        s0 += v.x; s1 += v.y; s2 += v.z; s3 += v.w;
    }
    float s = (s0 + s1) + (s2 + s3);
    for (int off = 32; off > 0; off >>= 1) s += __shfl_down(s, off, 64);
    __shared__ float red[4];
    int lane = t & 63, wid = t >> 6;
    if (lane == 0) red[wid] = s;
    __syncthreads();
    if (t == 0) {
        float tt = (red[0] + red[1]) + (red[2] + red[3]);
        xfeat[plane] = tt / (float)PLANE;
    }
}

// ---- Kernel 2: fused PLIF + fill. Each block (b,c) redundantly recomputes the
// sample-b PLIF (bit-identical across blocks), then channel c's 9 border-class
// values in LDS, then fills its plane with NT stores. No intermediate global. --
__global__ __launch_bounds__(256) void plif_fill_kernel(
        const float* __restrict__ xfeat,
        const float* __restrict__ w_in,
        const float* __restrict__ bn1_gamma, const float* __restrict__ bn1_beta,
        const float* __restrict__ bn1_mean,  const float* __restrict__ bn1_var,
        const float* __restrict__ decay_param, const float* __restrict__ v_th,
        const float* __restrict__ w_out, const float* __restrict__ conv_w,
        const float* __restrict__ bn2_gamma, const float* __restrict__ bn2_beta,
        const float* __restrict__ bn2_mean,  const float* __restrict__ bn2_var,
        const float* __restrict__ scale,
        float* __restrict__ out) {
    const int plane = blockIdx.x;          // b*CC + c
    const int b = plane >> 6;
    const int c = plane & 63;
    const int h = threadIdx.x;             // hidden unit 0..255

    __shared__ float  xf[CC];
    __shared__ double redd[4];
    __shared__ float  sbin[HIDN];
    __shared__ double bmp[4];
    __shared__ double modv_s;
    __shared__ float  v[9];

    if (h < CC) xf[h] = xfeat[b * CC + h];
    __syncthreads();

    // h_vec = x_feat @ w_in.T  (w_in is (HID, C) row-major); keep serial order
    double hv = 0.0;
    #pragma unroll 8
    for (int cc2 = 0; cc2 < CC; ++cc2)
        hv += (double)xf[cc2] * (double)w_in[h * CC + cc2];

    // BN1 (eval) + ReLU
    hv = (hv - (double)bn1_mean[h]) / sqrt((double)bn1_var[h] + 1e-5)
             * (double)bn1_gamma[h] + (double)bn1_beta[h];
    if (hv < 0.0) hv = 0.0;

    double d   = 1.0 / (1.0 + exp(-(double)decay_param[0]));
    double vth = (double)v_th[0];

    // PLIF recurrence, T = 4 (order-identical to the absmax-passing version)
    double mem_s = 0.0, sp_s = 0.0, spike = 0.0;
    int lane = h & 63, wid = h >> 6;
    for (int t = 0; t < 4; ++t) {
        double mem = d * (mem_s - vth * sp_s) + hv;
        double a = fabs(mem);
        for (int off = 32; off > 0; off >>= 1) a += __shfl_down(a, off, 64);
        if (lane == 0) redd[wid] = a;
        __syncthreads();
        double denom = ((redd[0] + redd[1]) + (redd[2] + redd[3])) / (double)HIDN + 1e-6;
        __syncthreads();
        mem = mem / denom;
        spike = (mem >= vth) ? 1.0 : 0.0;
        mem_s = mem;
        sp_s  = spike;
    }

    sbin[h] = (float)(2.0 * spike - 1.0);   // exactly +-1
    __syncthreads();

    // binary @ w_out.T for THIS channel only: 4 partial dots (same split/order
    // as the reference kernel's part = h>>6 decomposition)
    if (h < 4) {
        const float* wr = w_out + c * HIDN + h * 64;
        const float* sb = sbin + h * 64;
        double bm = 0.0;
        #pragma unroll 8
        for (int k = 0; k < 64; ++k)
            bm += (double)sb[k] * (double)wr[k];
        bmp[h] = bm;
    }
    __syncthreads();
    if (h == 0) {
        double t = ((bmp[0] + bmp[1]) + bmp[2]) + bmp[3];
        modv_s = 1.0 + tanh((double)scale[c] * t) * 0.5;
    }
    __syncthreads();

    // 9 border classes for this channel
    if (h < 9) {
        int rc = h / 3, cc2 = h - rc * 3;
        int kh0 = (rc == 0) ? 1 : 0, kh1 = (rc == 2) ? 1 : 2;
        int kw0 = (cc2 == 0) ? 1 : 0, kw1 = (cc2 == 2) ? 1 : 2;
        double S = 0.0;
        for (int kh = kh0; kh <= kh1; ++kh)
            for (int kw = kw0; kw <= kw1; ++kw)
                S += (double)conv_w[c * 9 + kh * 3 + kw];
        double y = modv_s * S;                                       // conv of const plane
        y = (y - (double)bn2_mean[c]) / sqrt((double)bn2_var[c] + 1e-5)
                * (double)bn2_gamma[c] + (double)bn2_beta[c];        // BN2 (eval)
        if (y < 0.0) y = 0.0;                                        // ReLU
        v[h] = (float)(1.0 + 0.25 * tanh(y));
    }
    __syncthreads();

    // single-pass branchy fill, NT stores (write-once, keep x resident in L3)
    fvec4* o4 = (fvec4*)(out + (size_t)plane * PLANE);
    for (int i = h; i < PLANE4; i += 256) {
        int r = i / ROW4;
        int q = i - r * ROW4;
        int base = (r == 0) ? 0 : ((r == HH - 1) ? 6 : 3);
        float m = v[base + 1];
        fvec4 val = { (q == 0) ? v[base] : m, m, m,
                      (q == ROW4 - 1) ? v[base + 2] : m };
        __builtin_nontemporal_store(val, &o4[i]);
    }
}

extern "C" void kernel_launch(void* const* d_in, const int* in_sizes, int n_in,
                              void* d_out, int out_size, void* d_ws, size_t ws_size,
                              hipStream_t stream) {
    const float* x          = (const float*)d_in[0];
    const float* w_in       = (const float*)d_in[1];
    const float* bn1_gamma  = (const float*)d_in[2];
    const float* bn1_beta   = (const float*)d_in[3];
    const float* bn1_mean   = (const float*)d_in[4];
    const float* bn1_var    = (const float*)d_in[5];
    const float* decay_p    = (const float*)d_in[6];
    const float* v_th       = (const float*)d_in[7];
    const float* w_out      = (const float*)d_in[8];
    const float* conv_w     = (const float*)d_in[9];
    const float* bn2_gamma  = (const float*)d_in[10];
    const float* bn2_beta   = (const float*)d_in[11];
    const float* bn2_mean   = (const float*)d_in[12];
    const float* bn2_var    = (const float*)d_in[13];
    const float* scale      = (const float*)d_in[14];
    float* out = (float*)d_out;

    float* xfeat = (float*)d_ws;            // 4096 floats

    pool_kernel<<<BB * CC, 256, 0, stream>>>(x, xfeat);
    plif_fill_kernel<<<BB * CC, 256, 0, stream>>>(
        xfeat, w_in, bn1_gamma, bn1_beta, bn1_mean, bn1_var, decay_p, v_th,
        w_out, conv_w, bn2_gamma, bn2_beta, bn2_mean, bn2_var, scale, out);
}